// Round 8
// baseline (42.571 us; speedup 1.0000x reference)
//
#include <hip/hip_runtime.h>

#define C_LEAF 2048
#define E_DIM  12
#define BLOCK  512   // 8 waves: 2x the waves/CU of the 256-thread version

__global__ __launch_bounds__(BLOCK, 6) void hll_per_sample(
    const float* __restrict__ inputs,    // [B, C_LEAF]
    const int*   __restrict__ target,    // [B]
    const float* __restrict__ onum,      // [C_ALL, C_LEAF, E]
    const float* __restrict__ oden,      // [C_ALL, C_LEAF, E]
    const float* __restrict__ weights,   // [C_ALL, E]
    float*       __restrict__ per_sample // [B]
) {
    const int b = blockIdx.x;
    const int t = target[b];

    const float* __restrict__ xrow = inputs + (size_t)b * C_LEAF;
    const float* __restrict__ nrow = onum + (size_t)t * C_LEAF * E_DIM;
    const float* __restrict__ drow = oden + (size_t)t * C_LEAF * E_DIM;

    float accn[E_DIM], accd[E_DIM];
#pragma unroll
    for (int e = 0; e < E_DIM; ++e) { accn[e] = 0.f; accd[e] = 0.f; }

    // C_LEAF / BLOCK = 4 iterations; compiler-scheduled (manual unroll
    // regressed in r6 via VGPR bloat)
    for (int c = threadIdx.x; c < C_LEAF; c += BLOCK) {
        const float x = xrow[c];
        const float4* __restrict__ n4 = (const float4*)(nrow + (size_t)c * E_DIM);
        const float4* __restrict__ d4 = (const float4*)(drow + (size_t)c * E_DIM);
#pragma unroll
        for (int q = 0; q < 3; ++q) {
            const float4 nv = n4[q];
            const float4 dv = d4[q];
            accn[4*q+0] += x * nv.x; accn[4*q+1] += x * nv.y;
            accn[4*q+2] += x * nv.z; accn[4*q+3] += x * nv.w;
            accd[4*q+0] += x * dv.x; accd[4*q+1] += x * dv.y;
            accd[4*q+2] += x * dv.z; accd[4*q+3] += x * dv.w;
        }
    }

    // intra-wave butterfly reduction (wave = 64 lanes)
#pragma unroll
    for (int e = 0; e < E_DIM; ++e) {
#pragma unroll
        for (int off = 32; off >= 1; off >>= 1) {
            accn[e] += __shfl_xor(accn[e], off, 64);
            accd[e] += __shfl_xor(accd[e], off, 64);
        }
    }

    // cross-wave via LDS (BLOCK/64 = 8 waves)
    __shared__ float sn[BLOCK/64][E_DIM];
    __shared__ float sd[BLOCK/64][E_DIM];
    const int wave = threadIdx.x >> 6;
    const int lane = threadIdx.x & 63;
    if (lane == 0) {
#pragma unroll
        for (int e = 0; e < E_DIM; ++e) { sn[wave][e] = accn[e]; sd[wave][e] = accd[e]; }
    }
    __syncthreads();

    if (threadIdx.x == 0) {
        const float* __restrict__ w = weights + (size_t)t * E_DIM;
        float s = 0.f;
#pragma unroll
        for (int e = 0; e < E_DIM; ++e) {
            float n = 0.f, d = 0.f;
#pragma unroll
            for (int wv = 0; wv < BLOCK/64; ++wv) { n += sn[wv][e]; d += sd[wv][e]; }
            if (n != 0.f) s += w[e] * (-__logf(n / d));
        }
        per_sample[b] = s;   // plain store: no fences, no atomics
    }
}

__global__ __launch_bounds__(256) void hll_reduce_mean(
    const float* __restrict__ per_sample, float* __restrict__ out, int n)
{
    float acc = 0.f;
    for (int i = threadIdx.x; i < n; i += 256) acc += per_sample[i];
#pragma unroll
    for (int off = 32; off >= 1; off >>= 1) acc += __shfl_xor(acc, off, 64);
    __shared__ float s[4];
    const int wave = threadIdx.x >> 6;
    const int lane = threadIdx.x & 63;
    if (lane == 0) s[wave] = acc;
    __syncthreads();
    if (threadIdx.x == 0) out[0] = (s[0] + s[1] + s[2] + s[3]) / (float)n;
}

extern "C" void kernel_launch(void* const* d_in, const int* in_sizes, int n_in,
                              void* d_out, int out_size, void* d_ws, size_t ws_size,
                              hipStream_t stream) {
    const float* inputs  = (const float*)d_in[0];
    const int*   target  = (const int*)  d_in[1];
    const float* onum    = (const float*)d_in[2];
    const float* oden    = (const float*)d_in[3];
    const float* weights = (const float*)d_in[4];
    float* out = (float*)d_out;

    const int B = in_sizes[1];           // target is [B]
    float* per_sample = (float*)d_ws;    // B floats of scratch

    hll_per_sample<<<B, BLOCK, 0, stream>>>(inputs, target, onum, oden, weights, per_sample);
    hll_reduce_mean<<<1, 256, 0, stream>>>(per_sample, out, B);
}